// Round 3
// baseline (1021.414 us; speedup 1.0000x reference)
//
#include <hip/hip_runtime.h>

// Problem dims
#define H_  256
#define I_  128
#define R_  32
#define B_  16
#define T_  48
#define H3_ 768

// d_out float offsets: (v, h, dU, trace_e, trace_E, outs, mods)
#define OFF_V    0
#define OFF_H    4096
#define OFF_DU   8192
#define OFF_TE   1056768
#define OFF_TT   1060864
#define OFF_OUTS 2109440
#define OFF_MODS 2306048

#define BAR_STRIDE 32          // ints; 128B between group counters

// Module-static scratch (allocated at .so load; zero-init counters).
// Avoids any dependence on d_ws sizing and on hipMemsetAsync.
__device__ __align__(16) float g_wx[T_*B_*H3_];   // LN(x@Wx^T+b) precomputed
__device__ __align__(16) float g_wh[2*B_*H3_];    // double-buffered h@Wh^T (+bias)
__device__ __align__(16) float g_pl[2*B_*H_];     // double-buffered plastic
__device__ int g_bar[B_*BAR_STRIDE];              // zero-init; self-reset at kernel end
__device__ int g_done[B_*BAR_STRIDE];

__device__ __forceinline__ float sigmf(float v){ return 1.0f/(1.0f+__expf(-v)); }

// 16-block group barrier with agent-scope fences (cross-XCD safe).
// __threadfence() lowers to s_waitcnt + buffer_wbl2/buffer_inv (cache-wide) —
// release/acquire for the whole CU/XCD from one wave.
__device__ __forceinline__ void groupbar(int* ctr, int target){
  __syncthreads();                     // all waves' stores issued before arrive
  if (threadIdx.x == 0){
    __threadfence();                   // release: flush my block's writes
    __hip_atomic_fetch_add(ctr, 1, __ATOMIC_RELAXED, __HIP_MEMORY_SCOPE_AGENT);
    while (__hip_atomic_load(ctr, __ATOMIC_RELAXED, __HIP_MEMORY_SCOPE_AGENT) < target)
      __builtin_amdgcn_s_sleep(1);
    __threadfence();                   // acquire: invalidate stale caches
  }
  __syncthreads();
}

__global__ __launch_bounds__(256, 1) void sgru_kernel(
    const float* __restrict__ x,     const float* __restrict__ h0,
    const float* __restrict__ v0,    const float* __restrict__ dU0,
    const float* __restrict__ te0,   const float* __restrict__ tE0,
    const float* __restrict__ Wx2h,  const float* __restrict__ bx2h,
    const float* __restrict__ Wh2h,  const float* __restrict__ bh2h,
    const float* __restrict__ lnxg,  const float* __restrict__ lnxb,
    const float* __restrict__ lnhg,  const float* __restrict__ lnhb,
    const float* __restrict__ Wh2mod,const float* __restrict__ bh2mod,
    const float* __restrict__ Wmod2h,const float* __restrict__ bmod2h,
    const float* __restrict__ alpha, const float* __restrict__ tauU,
    float* __restrict__ out)
{
  const int tid  = threadIdx.x;
  const int g    = blockIdx.x;
  const int b    = g >> 4;   // batch
  const int c    = g & 15;   // chunk within batch group
  const int lane = tid & 63;
  const int wv   = tid >> 6;

  __shared__ __align__(16) float h_s[H_], v_s[H_], te_s[H_], hn_s[H_], ten_s[H_];
  __shared__ __align__(16) float pre_s[H3_];           // also reused as x staging in init
  __shared__ __align__(16) float lnhg_s[H3_], lnhb_s[H3_];
  __shared__ __align__(16) float wrow_s[48*260];       // 48 Wh2h rows (stride 260 = bank spread)
  __shared__ float mod_s[R_];
  __shared__ float red_s[8];
  __shared__ float sm_s[2];

  float* ws_wx = g_wx;
  float* ws_wh = g_wh;
  float* ws_pl = g_pl;
  int*   ctr   = g_bar  + b*BAR_STRIDE;
  int*   dctr  = g_done + b*BAR_STRIDE;

  const float sp_a    = log1pf(__expf(alpha[0]));   // softplus(alpha)
  const float inv_spa = 1.0f / sp_a;
  const float tau     = sigmf(tauU[0]);

  // ---------------- init: states + weight staging ----------------
  for (int idx = tid; idx < H_; idx += 256){
    h_s[idx]  = h0[b*H_+idx];
    v_s[idx]  = v0[b*H_+idx];
    te_s[idx] = te0[b*H_+idx];
  }
  for (int idx = tid; idx < 48*256; idx += 256){
    int d = idx >> 8, e = idx & 255;
    wrow_s[d*260 + e] = Wh2h[((size_t)(c*48 + d))*H_ + e];
  }
  for (int idx = tid; idx < H3_; idx += 256){
    lnhg_s[idx] = lnhg[idx];
    lnhb_s[idx] = lnhb[idx];
  }
  // persistent per-thread registers (1 block/CU -> huge VGPR budget)
  float4 wreg[4];                       // clip rows Wv[i,:] for my 4 owned rows
  #pragma unroll
  for (int rr = 0; rr < 4; rr++){
    int i = c*16 + rr*4 + wv;
    wreg[rr] = ((const float4*)(Wh2h + ((size_t)(2*H_ + i))*H_))[lane];
  }
  const int mk = tid >> 3;              // mod row 0..31
  const int l8 = tid & 7;
  float4 wm[8];                         // Wh2mod[mk, l8*32 .. l8*32+32)
  #pragma unroll
  for (int u = 0; u < 8; u++)
    wm[u] = ((const float4*)(Wh2mod + (size_t)mk*H_))[l8*8 + u];
  const float bh2m = bh2mod[mk];
  float wmA = 0.f, wmB = 0.f, bm0 = 0.f, bm1 = 0.f;
  if (tid < 32){ wmA = Wmod2h[tid]; wmB = Wmod2h[R_+tid]; bm0 = bmod2h[0]; bm1 = bmod2h[1]; }
  float bh2h_reg = 0.f;
  if (tid < 192) bh2h_reg = bh2h[c*48 + (tid>>2)];
  __syncthreads();

  // ---- init: Wx_ln rows t = c*3+q for batch b (carry-independent, precompute all T)
  {
    float* xr = pre_s;   // reuse as [3][128]
    for (int idx = tid; idx < 3*I_; idx += 256){
      int q = idx >> 7, e = idx & 127;
      xr[q*I_ + e] = x[((size_t)((c*3+q)*B_ + b))*I_ + e];
    }
    __syncthreads();
    float acc[3][3];
    #pragma unroll
    for (int k = 0; k < 3; k++){
      acc[k][0]=0.f; acc[k][1]=0.f; acc[k][2]=0.f;
      int f = tid + 256*k;
      const float4* wr = (const float4*)(Wx2h + (size_t)f*I_);
      for (int e4 = 0; e4 < I_/4; e4++){
        float4 w4 = wr[e4];
        int e = e4*4;
        #pragma unroll
        for (int q = 0; q < 3; q++){
          float t0 = fmaf(w4.x, xr[q*I_+e],   acc[k][q]);
          t0       = fmaf(w4.y, xr[q*I_+e+1], t0);
          t0       = fmaf(w4.z, xr[q*I_+e+2], t0);
          acc[k][q]= fmaf(w4.w, xr[q*I_+e+3], t0);
        }
      }
      float bf = bx2h[f];
      acc[k][0]+=bf; acc[k][1]+=bf; acc[k][2]+=bf;
    }
    __syncthreads();
    for (int q = 0; q < 3; q++){
      float s1 = acc[0][q]+acc[1][q]+acc[2][q];
      float s2 = acc[0][q]*acc[0][q]+acc[1][q]*acc[1][q]+acc[2][q]*acc[2][q];
      #pragma unroll
      for (int off=32; off>0; off>>=1){ s1 += __shfl_xor(s1,off); s2 += __shfl_xor(s2,off); }
      if (lane==0){ red_s[wv]=s1; red_s[4+wv]=s2; }
      __syncthreads();
      s1 = red_s[0]+red_s[1]+red_s[2]+red_s[3];
      s2 = red_s[4]+red_s[5]+red_s[6]+red_s[7];
      __syncthreads();
      float mu  = s1*(1.0f/768.0f);
      float var = s2*(1.0f/768.0f) - mu*mu;
      float rs  = rsqrtf(var + 1e-5f);
      float* dst = ws_wx + ((size_t)((c*3+q)*B_ + b))*H3_;
      #pragma unroll
      for (int k = 0; k < 3; k++){
        int f = tid + 256*k;
        dst[f] = (acc[k][q]-mu)*rs*lnxg[f] + lnxb[f];
      }
    }
  }

  // ---- init: plastic_0 = sp_a * dU0 @ h0 for my 16 rows; Wh_raw_0 for my 48 features
  {
    const float4* h4 = (const float4*)h_s;
    float4 hj = h4[lane];
    #pragma unroll
    for (int rr = 0; rr < 4; rr++){
      int i = c*16 + rr*4 + wv;
      float4 du = ((const float4*)(dU0 + ((size_t)(b*H_+i))*H_))[lane];
      float acc = du.x*hj.x + du.y*hj.y + du.z*hj.z + du.w*hj.w;
      #pragma unroll
      for (int off=32; off>0; off>>=1) acc += __shfl_xor(acc,off);
      if (lane==0) ws_pl[b*H_ + i] = sp_a*acc;
    }
    if (tid < 192){
      int d = tid>>2, l4 = tid&3;
      const float4* wr4 = (const float4*)(wrow_s + d*260);
      const float4* hh4 = (const float4*)h_s;
      float acc = 0.f;
      #pragma unroll
      for (int u = 0; u < 16; u++){
        float4 w4 = wr4[l4*16+u];
        float4 hv = hh4[l4*16+u];
        acc = fmaf(w4.x,hv.x, fmaf(w4.y,hv.y, fmaf(w4.z,hv.z, fmaf(w4.w,hv.w, acc))));
      }
      acc += __shfl_xor(acc,1);
      acc += __shfl_xor(acc,2);
      if (l4==0) ws_wh[b*H3_ + c*48 + d] = acc + bh2h_reg;
    }
  }
  int target = 16;
  groupbar(ctr, target);

  // ---------------- scan ----------------
  for (int t = 0; t < T_; t++){
    const int p  = t & 1;
    const int pn = p ^ 1;

    // ---- G phase (redundant across the 16 blocks of this batch group)
    float wh0, wh1, wh2;
    {
      const float* whr = ws_wh + p*(B_*H3_) + b*H3_;
      const float* pl  = ws_pl + p*(B_*H_)  + b*H_;
      wh0 = whr[tid];
      wh1 = whr[tid+256];
      wh2 = whr[tid+512] + pl[tid];          // plastic added to v-slice pre-LN
      float s1 = wh0+wh1+wh2;
      float s2 = wh0*wh0+wh1*wh1+wh2*wh2;
      #pragma unroll
      for (int off=32; off>0; off>>=1){ s1 += __shfl_xor(s1,off); s2 += __shfl_xor(s2,off); }
      if (lane==0){ red_s[wv]=s1; red_s[4+wv]=s2; }
      __syncthreads();
      s1 = red_s[0]+red_s[1]+red_s[2]+red_s[3];
      s2 = red_s[4]+red_s[5]+red_s[6]+red_s[7];
      __syncthreads();
      float mu  = s1*(1.0f/768.0f);
      float var = s2*(1.0f/768.0f) - mu*mu;
      float rs  = rsqrtf(var + 1e-5f);
      const float* wxr = ws_wx + ((size_t)(t*B_ + b))*H3_;
      pre_s[tid]     = wxr[tid]     + (wh0-mu)*rs*lnhg_s[tid]     + lnhb_s[tid];
      pre_s[tid+256] = wxr[tid+256] + (wh1-mu)*rs*lnhg_s[tid+256] + lnhb_s[tid+256];
      pre_s[tid+512] = wxr[tid+512] + (wh2-mu)*rs*lnhg_s[tid+512] + lnhb_s[tid+512];
    }
    // gates (same-thread indices only; no sync needed before)
    {
      float z   = sigmf(pre_s[tid]);
      float r   = sigmf(pre_s[H_+tid]);
      float dv  = pre_s[2*H_+tid];
      float vo  = v_s[tid];
      float vn  = fmaf(z, dv - vo, vo);       // (1-z)v + z dv
      float hn  = fmaxf(vn, 0.0f);
      float teo = te_s[tid];
      float ten = fmaf(r, h_s[tid] - teo, teo);  // (1-r)te + r h_old
      v_s[tid] = vn; hn_s[tid] = hn; ten_s[tid] = ten;
      h_s[tid] = hn; te_s[tid] = ten;
    }
    __syncthreads();
    // mod = relu(h_new @ Wh2mod^T + b)
    {
      const float4* hn4 = (const float4*)hn_s;
      float acc = 0.f;
      #pragma unroll
      for (int u = 0; u < 8; u++){
        float4 hv = hn4[l8*8+u];
        float4 w4 = wm[u];
        acc = fmaf(w4.x,hv.x, fmaf(w4.y,hv.y, fmaf(w4.z,hv.z, fmaf(w4.w,hv.w, acc))));
      }
      acc += __shfl_xor(acc,1); acc += __shfl_xor(acc,2); acc += __shfl_xor(acc,4);
      if (l8==0) mod_s[mk] = fmaxf(acc + bh2m, 0.0f);
    }
    __syncthreads();
    if (tid < 32){
      float mv = mod_s[tid];
      float p0 = mv*wmA, p1 = mv*wmB;
      #pragma unroll
      for (int off=16; off>0; off>>=1){ p0 += __shfl_xor(p0,off); p1 += __shfl_xor(p1,off); }
      if (tid==0){ sm_s[0] = sigmf(p0+bm0); sm_s[1] = p1+bm1; }
    }
    __syncthreads();
    const float s_b = sm_s[0];
    const float m_b = sm_s[1];

    if (c == 0){   // designated writer for this batch
      out[OFF_OUTS + ((size_t)(t*B_+b))*H_ + tid] = hn_s[tid];
      if (tid < R_) out[OFF_MODS + (size_t)(t*B_+b)*R_ + tid] = mod_s[tid];
      if (t == T_-1){
        out[OFF_V  + b*H_ + tid] = v_s[tid];
        out[OFF_H  + b*H_ + tid] = hn_s[tid];
        out[OFF_TE + b*H_ + tid] = ten_s[tid];
      }
    }

    // ---- U phase: in-place tE/dU update for my 16 rows, fused plastic_{t+1}
    {
      const float4* hn4 = (const float4*)hn_s;
      const float4* te4 = (const float4*)ten_s;
      float4 hj = hn4[lane];
      float4 tj = te4[lane];
      const float* dsrc_base = (t==0) ? dU0 : (out + OFF_DU);
      const float* tsrc_base = (t==0) ? tE0 : (out + OFF_TT);
      #pragma unroll
      for (int rr = 0; rr < 4; rr++){
        int i = c*16 + rr*4 + wv;
        size_t rowo = ((size_t)(b*H_ + i))*H_;
        float4 du = ((const float4*)(dsrc_base + rowo))[lane];
        float4 tE = ((const float4*)(tsrc_base + rowo))[lane];
        float4 w  = wreg[rr];
        float hni  = hn_s[i];
        float teni = ten_s[i];
        float4 nd, nt;
        float acc;
        { float o_ = hni*tj.x - teni*hj.x;
          float tn = fmaf(s_b, o_ - tE.x, tE.x);
          float dn = fmaf(tau, fmaf(m_b, tn, -du.x), du.x);
          float up =  fmaxf(1.0f - w.x, 0.0f)*inv_spa;
          float lo = -fmaxf(1.0f + w.x, 0.0f)*inv_spa;
          dn = fminf(dn, up); dn = fmaxf(dn, lo);
          nt.x = tn; nd.x = dn; acc = dn*hj.x; }
        { float o_ = hni*tj.y - teni*hj.y;
          float tn = fmaf(s_b, o_ - tE.y, tE.y);
          float dn = fmaf(tau, fmaf(m_b, tn, -du.y), du.y);
          float up =  fmaxf(1.0f - w.y, 0.0f)*inv_spa;
          float lo = -fmaxf(1.0f + w.y, 0.0f)*inv_spa;
          dn = fminf(dn, up); dn = fmaxf(dn, lo);
          nt.y = tn; nd.y = dn; acc = fmaf(dn, hj.y, acc); }
        { float o_ = hni*tj.z - teni*hj.z;
          float tn = fmaf(s_b, o_ - tE.z, tE.z);
          float dn = fmaf(tau, fmaf(m_b, tn, -du.z), du.z);
          float up =  fmaxf(1.0f - w.z, 0.0f)*inv_spa;
          float lo = -fmaxf(1.0f + w.z, 0.0f)*inv_spa;
          dn = fminf(dn, up); dn = fmaxf(dn, lo);
          nt.z = tn; nd.z = dn; acc = fmaf(dn, hj.z, acc); }
        { float o_ = hni*tj.w - teni*hj.w;
          float tn = fmaf(s_b, o_ - tE.w, tE.w);
          float dn = fmaf(tau, fmaf(m_b, tn, -du.w), du.w);
          float up =  fmaxf(1.0f - w.w, 0.0f)*inv_spa;
          float lo = -fmaxf(1.0f + w.w, 0.0f)*inv_spa;
          dn = fminf(dn, up); dn = fmaxf(dn, lo);
          nt.w = tn; nd.w = dn; acc = fmaf(dn, hj.w, acc); }
        ((float4*)(out + OFF_DU + rowo))[lane] = nd;
        ((float4*)(out + OFF_TT + rowo))[lane] = nt;
        #pragma unroll
        for (int off=32; off>0; off>>=1) acc += __shfl_xor(acc,off);
        if (lane==0) ws_pl[pn*(B_*H_) + b*H_ + i] = sp_a*acc;   // plastic for t+1
      }
    }

    // ---- Wh_raw for t+1 (my 48 features, own batch, W from LDS) + barrier
    if (t < T_-1){
      if (tid < 192){
        int d = tid>>2, l4 = tid&3;
        const float4* wr4 = (const float4*)(wrow_s + d*260);
        const float4* hh4 = (const float4*)hn_s;
        float acc = 0.f;
        #pragma unroll
        for (int u = 0; u < 16; u++){
          float4 w4 = wr4[l4*16+u];
          float4 hv = hh4[l4*16+u];
          acc = fmaf(w4.x,hv.x, fmaf(w4.y,hv.y, fmaf(w4.z,hv.z, fmaf(w4.w,hv.w, acc))));
        }
        acc += __shfl_xor(acc,1);
        acc += __shfl_xor(acc,2);
        if (l4==0) ws_wh[pn*(B_*H3_) + b*H3_ + c*48 + d] = acc + bh2h_reg;
      }
      target += 16;
      groupbar(ctr, target);
    }
  }

  // ---- self-reset of group counters for the next launch.
  // done==16 requires every block past its final poll, so resetting ctr here
  // cannot strand a poller.
  __syncthreads();
  if (threadIdx.x == 0){
    int d = __hip_atomic_fetch_add(dctr, 1, __ATOMIC_RELAXED, __HIP_MEMORY_SCOPE_AGENT);
    if (d == 15){
      __hip_atomic_store(ctr,  0, __ATOMIC_RELAXED, __HIP_MEMORY_SCOPE_AGENT);
      __hip_atomic_store(dctr, 0, __ATOMIC_RELAXED, __HIP_MEMORY_SCOPE_AGENT);
    }
  }
}

extern "C" void kernel_launch(void* const* d_in, const int* in_sizes, int n_in,
                              void* d_out, int out_size, void* d_ws, size_t ws_size,
                              hipStream_t stream)
{
  const float* x      = (const float*)d_in[0];
  const float* h0     = (const float*)d_in[1];
  const float* v0     = (const float*)d_in[2];
  const float* dU0    = (const float*)d_in[3];
  const float* te0    = (const float*)d_in[4];
  const float* tE0    = (const float*)d_in[5];
  const float* Wx2h   = (const float*)d_in[6];
  const float* bx2h   = (const float*)d_in[7];
  const float* Wh2h   = (const float*)d_in[8];
  const float* bh2h   = (const float*)d_in[9];
  const float* lnxg   = (const float*)d_in[10];
  const float* lnxb   = (const float*)d_in[11];
  const float* lnhg   = (const float*)d_in[12];
  const float* lnhb   = (const float*)d_in[13];
  const float* Wh2mod = (const float*)d_in[14];
  const float* bh2mod = (const float*)d_in[15];
  const float* Wmod2h = (const float*)d_in[16];
  const float* bmod2h = (const float*)d_in[17];
  const float* alpha  = (const float*)d_in[18];
  const float* tauU   = (const float*)d_in[19];
  float* out = (float*)d_out;

  sgru_kernel<<<dim3(256), dim3(256), 0, stream>>>(
      x, h0, v0, dU0, te0, tE0, Wx2h, bx2h, Wh2h, bh2h,
      lnxg, lnxb, lnhg, lnhb, Wh2mod, bh2mod, Wmod2h, bmod2h,
      alpha, tauU, out);
}

// Round 4
// 749.090 us; speedup vs baseline: 1.3635x; 1.3635x over previous
//
#include <hip/hip_runtime.h>

// Problem dims
#define H_  256
#define I_  128
#define R_  32
#define B_  16
#define T_  48
#define H3_ 768

// d_out float offsets: (v, h, dU, trace_e, trace_E, outs, mods)
#define OFF_V    0
#define OFF_H    4096
#define OFF_DU   8192
#define OFF_TE   1056768
#define OFF_TT   1060864
#define OFF_OUTS 2109440
#define OFF_MODS 2306048

#define BAR_STRIDE 32          // ints; 128B between group counters

// Module-static scratch (allocated at .so load; zero-init counters).
__device__ __align__(16) float g_wx[T_*B_*H3_];   // LN(x@Wx^T+b) precomputed
__device__ __align__(16) float g_wh[2*B_*H3_];    // double-buffered h@Wh^T (+bias)
__device__ __align__(16) float g_pl[2*B_*H_];     // double-buffered plastic
__device__ int g_bar[B_*BAR_STRIDE];              // zero-init; self-reset at kernel end
__device__ int g_done[B_*BAR_STRIDE];

__device__ __forceinline__ float sigmf(float v){ return 1.0f/(1.0f+__expf(-v)); }

// 16-block group barrier with agent-scope fences (cross-XCD safe).
// With dU/tE in registers, the dirty-L2 volume behind the wbl2 is tiny
// (only the 4 KB/batch exchange), so the fence runs at its fixed latency.
__device__ __forceinline__ void groupbar(int* ctr, int target){
  __syncthreads();                     // all waves' stores issued before arrive
  if (threadIdx.x == 0){
    __threadfence();                   // release: flush my block's writes
    __hip_atomic_fetch_add(ctr, 1, __ATOMIC_RELAXED, __HIP_MEMORY_SCOPE_AGENT);
    while (__hip_atomic_load(ctr, __ATOMIC_RELAXED, __HIP_MEMORY_SCOPE_AGENT) < target)
      __builtin_amdgcn_s_sleep(1);
    __threadfence();                   // acquire: invalidate stale caches
  }
  __syncthreads();
}

__global__ __launch_bounds__(256, 1) void sgru_kernel(
    const float* __restrict__ x,     const float* __restrict__ h0,
    const float* __restrict__ v0,    const float* __restrict__ dU0,
    const float* __restrict__ te0,   const float* __restrict__ tE0,
    const float* __restrict__ Wx2h,  const float* __restrict__ bx2h,
    const float* __restrict__ Wh2h,  const float* __restrict__ bh2h,
    const float* __restrict__ lnxg,  const float* __restrict__ lnxb,
    const float* __restrict__ lnhg,  const float* __restrict__ lnhb,
    const float* __restrict__ Wh2mod,const float* __restrict__ bh2mod,
    const float* __restrict__ Wmod2h,const float* __restrict__ bmod2h,
    const float* __restrict__ alpha, const float* __restrict__ tauU,
    float* __restrict__ out)
{
  const int tid  = threadIdx.x;
  const int g    = blockIdx.x;
  const int b    = g >> 4;   // batch
  const int c    = g & 15;   // chunk within batch group
  const int lane = tid & 63;
  const int wv   = tid >> 6;

  __shared__ __align__(16) float h_s[H_], v_s[H_], te_s[H_], hn_s[H_], ten_s[H_];
  __shared__ __align__(16) float pre_s[H3_];           // also reused as x staging in init
  __shared__ __align__(16) float lnhg_s[H3_], lnhb_s[H3_];
  __shared__ __align__(16) float wrow_s[48*260];       // 48 Wh2h rows (stride 260 = bank spread)
  __shared__ float mod_s[R_];
  __shared__ float red_s[8];
  __shared__ float sm_s[2];

  float* ws_wx = g_wx;
  float* ws_wh = g_wh;
  float* ws_pl = g_pl;
  int*   ctr   = g_bar  + b*BAR_STRIDE;
  int*   dctr  = g_done + b*BAR_STRIDE;

  const float sp_a    = log1pf(__expf(alpha[0]));   // softplus(alpha)
  const float inv_spa = 1.0f / sp_a;
  const float tau     = sigmf(tauU[0]);

  // ---------------- init: states + weight staging ----------------
  for (int idx = tid; idx < H_; idx += 256){
    h_s[idx]  = h0[b*H_+idx];
    v_s[idx]  = v0[b*H_+idx];
    te_s[idx] = te0[b*H_+idx];
  }
  for (int idx = tid; idx < 48*256; idx += 256){
    int d = idx >> 8, e = idx & 255;
    wrow_s[d*260 + e] = Wh2h[((size_t)(c*48 + d))*H_ + e];
  }
  for (int idx = tid; idx < H3_; idx += 256){
    lnhg_s[idx] = lnhg[idx];
    lnhb_s[idx] = lnhb[idx];
  }
  // persistent per-thread registers (1 block/CU -> huge VGPR budget)
  float4 wreg[4];                       // clip rows Wv[i,:] for my 4 owned rows
  float4 duR[4], tER[4];                // PERSISTENT dU/tE fragments (my 16 rows)
  #pragma unroll
  for (int rr = 0; rr < 4; rr++){
    int i = c*16 + rr*4 + wv;
    wreg[rr] = ((const float4*)(Wh2h + ((size_t)(2*H_ + i))*H_))[lane];
    size_t rowo = ((size_t)(b*H_ + i))*H_;
    duR[rr] = ((const float4*)(dU0 + rowo))[lane];
    tER[rr] = ((const float4*)(tE0 + rowo))[lane];
  }
  const int mk = tid >> 3;              // mod row 0..31
  const int l8 = tid & 7;
  float4 wm[8];                         // Wh2mod[mk, l8*32 .. l8*32+32)
  #pragma unroll
  for (int u = 0; u < 8; u++)
    wm[u] = ((const float4*)(Wh2mod + (size_t)mk*H_))[l8*8 + u];
  const float bh2m = bh2mod[mk];
  float wmA = 0.f, wmB = 0.f, bm0 = 0.f, bm1 = 0.f;
  if (tid < 32){ wmA = Wmod2h[tid]; wmB = Wmod2h[R_+tid]; bm0 = bmod2h[0]; bm1 = bmod2h[1]; }
  float bh2h_reg = 0.f;
  if (tid < 192) bh2h_reg = bh2h[c*48 + (tid>>2)];
  __syncthreads();

  // ---- init: Wx_ln rows t = c*3+q for batch b (carry-independent, precompute all T)
  {
    float* xr = pre_s;   // reuse as [3][128]
    for (int idx = tid; idx < 3*I_; idx += 256){
      int q = idx >> 7, e = idx & 127;
      xr[q*I_ + e] = x[((size_t)((c*3+q)*B_ + b))*I_ + e];
    }
    __syncthreads();
    float acc[3][3];
    #pragma unroll
    for (int k = 0; k < 3; k++){
      acc[k][0]=0.f; acc[k][1]=0.f; acc[k][2]=0.f;
      int f = tid + 256*k;
      const float4* wr = (const float4*)(Wx2h + (size_t)f*I_);
      for (int e4 = 0; e4 < I_/4; e4++){
        float4 w4 = wr[e4];
        int e = e4*4;
        #pragma unroll
        for (int q = 0; q < 3; q++){
          float t0 = fmaf(w4.x, xr[q*I_+e],   acc[k][q]);
          t0       = fmaf(w4.y, xr[q*I_+e+1], t0);
          t0       = fmaf(w4.z, xr[q*I_+e+2], t0);
          acc[k][q]= fmaf(w4.w, xr[q*I_+e+3], t0);
        }
      }
      float bf = bx2h[f];
      acc[k][0]+=bf; acc[k][1]+=bf; acc[k][2]+=bf;
    }
    __syncthreads();
    for (int q = 0; q < 3; q++){
      float s1 = acc[0][q]+acc[1][q]+acc[2][q];
      float s2 = acc[0][q]*acc[0][q]+acc[1][q]*acc[1][q]+acc[2][q]*acc[2][q];
      #pragma unroll
      for (int off=32; off>0; off>>=1){ s1 += __shfl_xor(s1,off); s2 += __shfl_xor(s2,off); }
      if (lane==0){ red_s[wv]=s1; red_s[4+wv]=s2; }
      __syncthreads();
      s1 = red_s[0]+red_s[1]+red_s[2]+red_s[3];
      s2 = red_s[4]+red_s[5]+red_s[6]+red_s[7];
      __syncthreads();
      float mu  = s1*(1.0f/768.0f);
      float var = s2*(1.0f/768.0f) - mu*mu;
      float rs  = rsqrtf(var + 1e-5f);
      float* dst = ws_wx + ((size_t)((c*3+q)*B_ + b))*H3_;
      #pragma unroll
      for (int k = 0; k < 3; k++){
        int f = tid + 256*k;
        dst[f] = (acc[k][q]-mu)*rs*lnxg[f] + lnxb[f];
      }
    }
  }

  // ---- init: plastic_0 = sp_a * dU0 @ h0 for my 16 rows; Wh_raw_0 for my 48 features
  {
    const float4* h4 = (const float4*)h_s;
    float4 hj = h4[lane];
    #pragma unroll
    for (int rr = 0; rr < 4; rr++){
      int i = c*16 + rr*4 + wv;
      float4 du = duR[rr];
      float acc = du.x*hj.x + du.y*hj.y + du.z*hj.z + du.w*hj.w;
      #pragma unroll
      for (int off=32; off>0; off>>=1) acc += __shfl_xor(acc,off);
      if (lane==0) ws_pl[b*H_ + i] = sp_a*acc;
    }
    if (tid < 192){
      int d = tid>>2, l4 = tid&3;
      const float4* wr4 = (const float4*)(wrow_s + d*260);
      const float4* hh4 = (const float4*)h_s;
      float acc = 0.f;
      #pragma unroll
      for (int u = 0; u < 16; u++){
        float4 w4 = wr4[l4*16+u];
        float4 hv = hh4[l4*16+u];
        acc = fmaf(w4.x,hv.x, fmaf(w4.y,hv.y, fmaf(w4.z,hv.z, fmaf(w4.w,hv.w, acc))));
      }
      acc += __shfl_xor(acc,1);
      acc += __shfl_xor(acc,2);
      if (l4==0) ws_wh[b*H3_ + c*48 + d] = acc + bh2h_reg;
    }
  }
  int target = 16;
  groupbar(ctr, target);

  // ---------------- scan ----------------
  for (int t = 0; t < T_; t++){
    const int p  = t & 1;
    const int pn = p ^ 1;

    // ---- G phase (redundant across the 16 blocks of this batch group)
    float wh0, wh1, wh2;
    {
      const float* whr = ws_wh + p*(B_*H3_) + b*H3_;
      const float* pl  = ws_pl + p*(B_*H_)  + b*H_;
      wh0 = whr[tid];
      wh1 = whr[tid+256];
      wh2 = whr[tid+512] + pl[tid];          // plastic added to v-slice pre-LN
      float s1 = wh0+wh1+wh2;
      float s2 = wh0*wh0+wh1*wh1+wh2*wh2;
      #pragma unroll
      for (int off=32; off>0; off>>=1){ s1 += __shfl_xor(s1,off); s2 += __shfl_xor(s2,off); }
      if (lane==0){ red_s[wv]=s1; red_s[4+wv]=s2; }
      __syncthreads();
      s1 = red_s[0]+red_s[1]+red_s[2]+red_s[3];
      s2 = red_s[4]+red_s[5]+red_s[6]+red_s[7];
      __syncthreads();
      float mu  = s1*(1.0f/768.0f);
      float var = s2*(1.0f/768.0f) - mu*mu;
      float rs  = rsqrtf(var + 1e-5f);
      const float* wxr = ws_wx + ((size_t)(t*B_ + b))*H3_;
      pre_s[tid]     = wxr[tid]     + (wh0-mu)*rs*lnhg_s[tid]     + lnhb_s[tid];
      pre_s[tid+256] = wxr[tid+256] + (wh1-mu)*rs*lnhg_s[tid+256] + lnhb_s[tid+256];
      pre_s[tid+512] = wxr[tid+512] + (wh2-mu)*rs*lnhg_s[tid+512] + lnhb_s[tid+512];
    }
    // gates (same-thread indices only; no sync needed before)
    {
      float z   = sigmf(pre_s[tid]);
      float r   = sigmf(pre_s[H_+tid]);
      float dv  = pre_s[2*H_+tid];
      float vo  = v_s[tid];
      float vn  = fmaf(z, dv - vo, vo);       // (1-z)v + z dv
      float hn  = fmaxf(vn, 0.0f);
      float teo = te_s[tid];
      float ten = fmaf(r, h_s[tid] - teo, teo);  // (1-r)te + r h_old
      v_s[tid] = vn; hn_s[tid] = hn; ten_s[tid] = ten;
      h_s[tid] = hn; te_s[tid] = ten;
    }
    __syncthreads();
    // mod = relu(h_new @ Wh2mod^T + b)
    {
      const float4* hn4 = (const float4*)hn_s;
      float acc = 0.f;
      #pragma unroll
      for (int u = 0; u < 8; u++){
        float4 hv = hn4[l8*8+u];
        float4 w4 = wm[u];
        acc = fmaf(w4.x,hv.x, fmaf(w4.y,hv.y, fmaf(w4.z,hv.z, fmaf(w4.w,hv.w, acc))));
      }
      acc += __shfl_xor(acc,1); acc += __shfl_xor(acc,2); acc += __shfl_xor(acc,4);
      if (l8==0) mod_s[mk] = fmaxf(acc + bh2m, 0.0f);
    }
    __syncthreads();
    if (tid < 32){
      float mv = mod_s[tid];
      float p0 = mv*wmA, p1 = mv*wmB;
      #pragma unroll
      for (int off=16; off>0; off>>=1){ p0 += __shfl_xor(p0,off); p1 += __shfl_xor(p1,off); }
      if (tid==0){ sm_s[0] = sigmf(p0+bm0); sm_s[1] = p1+bm1; }
    }
    __syncthreads();
    const float s_b = sm_s[0];
    const float m_b = sm_s[1];

    if (c == 0){   // designated writer for this batch
      out[OFF_OUTS + ((size_t)(t*B_+b))*H_ + tid] = hn_s[tid];
      if (tid < R_) out[OFF_MODS + (size_t)(t*B_+b)*R_ + tid] = mod_s[tid];
      if (t == T_-1){
        out[OFF_V  + b*H_ + tid] = v_s[tid];
        out[OFF_H  + b*H_ + tid] = hn_s[tid];
        out[OFF_TE + b*H_ + tid] = ten_s[tid];
      }
    }

    // ---- U phase: register-resident tE/dU update for my 16 rows,
    //      fused plastic_{t+1}; global write ONLY at the final step.
    {
      const float4* hn4 = (const float4*)hn_s;
      const float4* te4 = (const float4*)ten_s;
      float4 hj = hn4[lane];
      float4 tj = te4[lane];
      #pragma unroll
      for (int rr = 0; rr < 4; rr++){
        int i = c*16 + rr*4 + wv;
        float4 du = duR[rr];
        float4 tE = tER[rr];
        float4 w  = wreg[rr];
        float hni  = hn_s[i];
        float teni = ten_s[i];
        float4 nd, nt;
        float acc;
        { float o_ = hni*tj.x - teni*hj.x;
          float tn = fmaf(s_b, o_ - tE.x, tE.x);
          float dn = fmaf(tau, fmaf(m_b, tn, -du.x), du.x);
          float up =  fmaxf(1.0f - w.x, 0.0f)*inv_spa;
          float lo = -fmaxf(1.0f + w.x, 0.0f)*inv_spa;
          dn = fminf(dn, up); dn = fmaxf(dn, lo);
          nt.x = tn; nd.x = dn; acc = dn*hj.x; }
        { float o_ = hni*tj.y - teni*hj.y;
          float tn = fmaf(s_b, o_ - tE.y, tE.y);
          float dn = fmaf(tau, fmaf(m_b, tn, -du.y), du.y);
          float up =  fmaxf(1.0f - w.y, 0.0f)*inv_spa;
          float lo = -fmaxf(1.0f + w.y, 0.0f)*inv_spa;
          dn = fminf(dn, up); dn = fmaxf(dn, lo);
          nt.y = tn; nd.y = dn; acc = fmaf(dn, hj.y, acc); }
        { float o_ = hni*tj.z - teni*hj.z;
          float tn = fmaf(s_b, o_ - tE.z, tE.z);
          float dn = fmaf(tau, fmaf(m_b, tn, -du.z), du.z);
          float up =  fmaxf(1.0f - w.z, 0.0f)*inv_spa;
          float lo = -fmaxf(1.0f + w.z, 0.0f)*inv_spa;
          dn = fminf(dn, up); dn = fmaxf(dn, lo);
          nt.z = tn; nd.z = dn; acc = fmaf(dn, hj.z, acc); }
        { float o_ = hni*tj.w - teni*hj.w;
          float tn = fmaf(s_b, o_ - tE.w, tE.w);
          float dn = fmaf(tau, fmaf(m_b, tn, -du.w), du.w);
          float up =  fmaxf(1.0f - w.w, 0.0f)*inv_spa;
          float lo = -fmaxf(1.0f + w.w, 0.0f)*inv_spa;
          dn = fminf(dn, up); dn = fmaxf(dn, lo);
          nt.w = tn; nd.w = dn; acc = fmaf(dn, hj.w, acc); }
        duR[rr] = nd;
        tER[rr] = nt;
        if (t == T_-1){
          size_t rowo = ((size_t)(b*H_ + i))*H_;
          ((float4*)(out + OFF_DU + rowo))[lane] = nd;
          ((float4*)(out + OFF_TT + rowo))[lane] = nt;
        }
        #pragma unroll
        for (int off=32; off>0; off>>=1) acc += __shfl_xor(acc,off);
        if (lane==0) ws_pl[pn*(B_*H_) + b*H_ + i] = sp_a*acc;   // plastic for t+1
      }
    }

    // ---- Wh_raw for t+1 (my 48 features, own batch, W from LDS) + barrier
    if (t < T_-1){
      if (tid < 192){
        int d = tid>>2, l4 = tid&3;
        const float4* wr4 = (const float4*)(wrow_s + d*260);
        const float4* hh4 = (const float4*)hn_s;
        float acc = 0.f;
        #pragma unroll
        for (int u = 0; u < 16; u++){
          float4 w4 = wr4[l4*16+u];
          float4 hv = hh4[l4*16+u];
          acc = fmaf(w4.x,hv.x, fmaf(w4.y,hv.y, fmaf(w4.z,hv.z, fmaf(w4.w,hv.w, acc))));
        }
        acc += __shfl_xor(acc,1);
        acc += __shfl_xor(acc,2);
        if (l4==0) ws_wh[pn*(B_*H3_) + b*H3_ + c*48 + d] = acc + bh2h_reg;
      }
      target += 16;
      groupbar(ctr, target);
    }
  }

  // ---- self-reset of group counters for the next launch.
  __syncthreads();
  if (threadIdx.x == 0){
    int d = __hip_atomic_fetch_add(dctr, 1, __ATOMIC_RELAXED, __HIP_MEMORY_SCOPE_AGENT);
    if (d == 15){
      __hip_atomic_store(ctr,  0, __ATOMIC_RELAXED, __HIP_MEMORY_SCOPE_AGENT);
      __hip_atomic_store(dctr, 0, __ATOMIC_RELAXED, __HIP_MEMORY_SCOPE_AGENT);
    }
  }
}

extern "C" void kernel_launch(void* const* d_in, const int* in_sizes, int n_in,
                              void* d_out, int out_size, void* d_ws, size_t ws_size,
                              hipStream_t stream)
{
  const float* x      = (const float*)d_in[0];
  const float* h0     = (const float*)d_in[1];
  const float* v0     = (const float*)d_in[2];
  const float* dU0    = (const float*)d_in[3];
  const float* te0    = (const float*)d_in[4];
  const float* tE0    = (const float*)d_in[5];
  const float* Wx2h   = (const float*)d_in[6];
  const float* bx2h   = (const float*)d_in[7];
  const float* Wh2h   = (const float*)d_in[8];
  const float* bh2h   = (const float*)d_in[9];
  const float* lnxg   = (const float*)d_in[10];
  const float* lnxb   = (const float*)d_in[11];
  const float* lnhg   = (const float*)d_in[12];
  const float* lnhb   = (const float*)d_in[13];
  const float* Wh2mod = (const float*)d_in[14];
  const float* bh2mod = (const float*)d_in[15];
  const float* Wmod2h = (const float*)d_in[16];
  const float* bmod2h = (const float*)d_in[17];
  const float* alpha  = (const float*)d_in[18];
  const float* tauU   = (const float*)d_in[19];
  float* out = (float*)d_out;

  sgru_kernel<<<dim3(256), dim3(256), 0, stream>>>(
      x, h0, v0, dU0, te0, tE0, Wx2h, bx2h, Wh2h, bh2h,
      lnxg, lnxb, lnhg, lnhb, Wh2mod, bh2mod, Wmod2h, bmod2h,
      alpha, tauU, out);
}

// Round 5
// 347.184 us; speedup vs baseline: 2.9420x; 2.1576x over previous
//
#include <hip/hip_runtime.h>

// Problem dims
#define H_  256
#define I_  128
#define R_  32
#define B_  16
#define T_  48
#define H3_ 768

// d_out float offsets: (v, h, dU, trace_e, trace_E, outs, mods)
#define OFF_V    0
#define OFF_H    4096
#define OFF_DU   8192
#define OFF_TE   1056768
#define OFF_TT   1060864
#define OFF_OUTS 2109440
#define OFF_MODS 2306048

#define BAR_STRIDE 32          // ints; 128B between group counters

// Module-static scratch (allocated at .so load; zero-init counters).
__device__ __align__(16) float g_wx[T_*B_*H3_];   // LN(x@Wx^T+b) precomputed
__device__ __align__(16) float g_wh[2*B_*H3_];    // double-buffered h@Wh^T (+bias) — sc1 mailbox
__device__ __align__(16) float g_pl[2*B_*H_];     // double-buffered plastic — sc1 mailbox
__device__ int g_bar[B_*BAR_STRIDE];              // zero-init; self-reset at kernel end
__device__ int g_done[B_*BAR_STRIDE];

__device__ __forceinline__ float sigmf(float v){ return 1.0f/(1.0f+__expf(-v)); }

// Coherent (agent-scope, sc1) mailbox accessors: per-access coherent, so the
// barrier needs NO cache-wide wbl2/inv in steady state.
__device__ __forceinline__ void cstore(float* p, float v){
  __hip_atomic_store(p, v, __ATOMIC_RELAXED, __HIP_MEMORY_SCOPE_AGENT);
}
__device__ __forceinline__ float cload(const float* p){
  return __hip_atomic_load(p, __ATOMIC_RELAXED, __HIP_MEMORY_SCOPE_AGENT);
}

// Full barrier (init only): publishes plain g_wx stores via cache-wide fence.
__device__ __forceinline__ void groupbar_full(int* ctr, int target){
  __syncthreads();
  if (threadIdx.x == 0){
    __threadfence();                   // release: wbl2 (flush plain g_wx writes)
    __hip_atomic_fetch_add(ctr, 1, __ATOMIC_RELAXED, __HIP_MEMORY_SCOPE_AGENT);
    while (__hip_atomic_load(ctr, __ATOMIC_RELAXED, __HIP_MEMORY_SCOPE_AGENT) < target)
      __builtin_amdgcn_s_sleep(1);
    __threadfence();                   // acquire: inv
  }
  __syncthreads();
}

// Light barrier (steady state): all cross-block data is sc1 atomics, already
// at the coherence point once vmcnt drains (which __syncthreads forces before
// s_barrier). No cache maintenance => fixed cost is just the L3 atomic RTT.
__device__ __forceinline__ void groupbar_light(int* ctr, int target){
  __syncthreads();                     // drains each wave's vmcnt (sc1 stores done)
  if (threadIdx.x == 0){
    __hip_atomic_fetch_add(ctr, 1, __ATOMIC_RELAXED, __HIP_MEMORY_SCOPE_AGENT);
    while (__hip_atomic_load(ctr, __ATOMIC_RELAXED, __HIP_MEMORY_SCOPE_AGENT) < target)
      __builtin_amdgcn_s_sleep(1);
    asm volatile("" ::: "memory");     // no compiler hoist of data loads above poll
  }
  __syncthreads();
}

__global__ __launch_bounds__(256, 1) void sgru_kernel(
    const float* __restrict__ x,     const float* __restrict__ h0,
    const float* __restrict__ v0,    const float* __restrict__ dU0,
    const float* __restrict__ te0,   const float* __restrict__ tE0,
    const float* __restrict__ Wx2h,  const float* __restrict__ bx2h,
    const float* __restrict__ Wh2h,  const float* __restrict__ bh2h,
    const float* __restrict__ lnxg,  const float* __restrict__ lnxb,
    const float* __restrict__ lnhg,  const float* __restrict__ lnhb,
    const float* __restrict__ Wh2mod,const float* __restrict__ bh2mod,
    const float* __restrict__ Wmod2h,const float* __restrict__ bmod2h,
    const float* __restrict__ alpha, const float* __restrict__ tauU,
    float* __restrict__ out)
{
  const int tid  = threadIdx.x;
  const int g    = blockIdx.x;
  const int b    = g >> 4;   // batch
  const int c    = g & 15;   // chunk within batch group
  const int lane = tid & 63;
  const int wv   = tid >> 6;

  __shared__ __align__(16) float h_s[H_], v_s[H_], te_s[H_], hn_s[H_], ten_s[H_];
  __shared__ __align__(16) float pre_s[H3_];           // also reused as x staging in init
  __shared__ __align__(16) float lnhg_s[H3_], lnhb_s[H3_];
  __shared__ __align__(16) float wrow_s[48*260];       // 48 Wh2h rows (stride 260)
  __shared__ float mod_s[R_];
  __shared__ float red_s[8];
  __shared__ float sm_s[2];

  float* ws_wx = g_wx;
  float* ws_wh = g_wh;
  float* ws_pl = g_pl;
  int*   ctr   = g_bar  + b*BAR_STRIDE;
  int*   dctr  = g_done + b*BAR_STRIDE;

  const float sp_a    = log1pf(__expf(alpha[0]));   // softplus(alpha)
  const float inv_spa = 1.0f / sp_a;
  const float tau     = sigmf(tauU[0]);

  // ---------------- init: states + weight staging ----------------
  for (int idx = tid; idx < H_; idx += 256){
    h_s[idx]  = h0[b*H_+idx];
    v_s[idx]  = v0[b*H_+idx];
    te_s[idx] = te0[b*H_+idx];
  }
  for (int idx = tid; idx < 48*256; idx += 256){
    int d = idx >> 8, e = idx & 255;
    wrow_s[d*260 + e] = Wh2h[((size_t)(c*48 + d))*H_ + e];
  }
  for (int idx = tid; idx < H3_; idx += 256){
    lnhg_s[idx] = lnhg[idx];
    lnhb_s[idx] = lnhb[idx];
  }
  // persistent per-thread registers (1 block/CU -> huge VGPR budget)
  float4 wreg[4];                       // clip rows Wv[i,:] for my 4 owned rows
  float4 duR[4], tER[4];                // PERSISTENT dU/tE fragments (my 16 rows)
  #pragma unroll
  for (int rr = 0; rr < 4; rr++){
    int i = c*16 + rr*4 + wv;
    wreg[rr] = ((const float4*)(Wh2h + ((size_t)(2*H_ + i))*H_))[lane];
    size_t rowo = ((size_t)(b*H_ + i))*H_;
    duR[rr] = ((const float4*)(dU0 + rowo))[lane];
    tER[rr] = ((const float4*)(tE0 + rowo))[lane];
  }
  const int mk = tid >> 3;              // mod row 0..31
  const int l8 = tid & 7;
  const int mk7 = mk & 7;               // swizzle key (bank spread)
  float4 wm[8];                         // Wh2mod[mk, chunk (j+mk)&7 of my 8]
  #pragma unroll
  for (int j = 0; j < 8; j++)
    wm[j] = ((const float4*)(Wh2mod + (size_t)mk*H_))[l8*8 + ((j+mk7)&7)];
  const float bh2m = bh2mod[mk];
  float wmA = 0.f, wmB = 0.f, bm0 = 0.f, bm1 = 0.f;
  if (tid < 32){ wmA = Wmod2h[tid]; wmB = Wmod2h[R_+tid]; bm0 = bmod2h[0]; bm1 = bmod2h[1]; }
  float bh2h_reg = 0.f;
  if (tid < 192) bh2h_reg = bh2h[c*48 + (tid>>2)];
  __syncthreads();

  // ---- init: Wx_ln rows t = c*3+q for batch b (carry-independent, precompute all T)
  {
    float* xr = pre_s;   // reuse as [3][128]
    for (int idx = tid; idx < 3*I_; idx += 256){
      int q = idx >> 7, e = idx & 127;
      xr[q*I_ + e] = x[((size_t)((c*3+q)*B_ + b))*I_ + e];
    }
    __syncthreads();
    float acc[3][3];
    #pragma unroll
    for (int k = 0; k < 3; k++){
      acc[k][0]=0.f; acc[k][1]=0.f; acc[k][2]=0.f;
      int f = tid + 256*k;
      const float4* wr = (const float4*)(Wx2h + (size_t)f*I_);
      for (int e4 = 0; e4 < I_/4; e4++){
        float4 w4 = wr[e4];
        int e = e4*4;
        #pragma unroll
        for (int q = 0; q < 3; q++){
          float t0 = fmaf(w4.x, xr[q*I_+e],   acc[k][q]);
          t0       = fmaf(w4.y, xr[q*I_+e+1], t0);
          t0       = fmaf(w4.z, xr[q*I_+e+2], t0);
          acc[k][q]= fmaf(w4.w, xr[q*I_+e+3], t0);
        }
      }
      float bf = bx2h[f];
      acc[k][0]+=bf; acc[k][1]+=bf; acc[k][2]+=bf;
    }
    __syncthreads();
    for (int q = 0; q < 3; q++){
      float s1 = acc[0][q]+acc[1][q]+acc[2][q];
      float s2 = acc[0][q]*acc[0][q]+acc[1][q]*acc[1][q]+acc[2][q]*acc[2][q];
      #pragma unroll
      for (int off=32; off>0; off>>=1){ s1 += __shfl_xor(s1,off); s2 += __shfl_xor(s2,off); }
      if (lane==0){ red_s[wv]=s1; red_s[4+wv]=s2; }
      __syncthreads();
      s1 = red_s[0]+red_s[1]+red_s[2]+red_s[3];
      s2 = red_s[4]+red_s[5]+red_s[6]+red_s[7];
      __syncthreads();
      float mu  = s1*(1.0f/768.0f);
      float var = s2*(1.0f/768.0f) - mu*mu;
      float rs  = rsqrtf(var + 1e-5f);
      float* dst = ws_wx + ((size_t)((c*3+q)*B_ + b))*H3_;
      #pragma unroll
      for (int k = 0; k < 3; k++){
        int f = tid + 256*k;
        dst[f] = (acc[k][q]-mu)*rs*lnxg[f] + lnxb[f];
      }
    }
  }

  // ---- init: plastic_0 = sp_a * dU0 @ h0 for my 16 rows; Wh_raw_0 for my 48 features
  {
    const float4* h4 = (const float4*)h_s;
    float4 hj = h4[lane];
    #pragma unroll
    for (int rr = 0; rr < 4; rr++){
      int i = c*16 + rr*4 + wv;
      float4 du = duR[rr];
      float acc = du.x*hj.x + du.y*hj.y + du.z*hj.z + du.w*hj.w;
      #pragma unroll
      for (int off=32; off>0; off>>=1) acc += __shfl_xor(acc,off);
      if (lane==0) cstore(&ws_pl[b*H_ + i], sp_a*acc);
    }
    if (tid < 192){
      int d = tid>>2, l4 = tid&3;
      const float4* wr4 = (const float4*)(wrow_s + d*260);
      const float4* hh4 = (const float4*)h_s;
      float acc = 0.f;
      #pragma unroll
      for (int u = 0; u < 16; u++){
        float4 w4 = wr4[l4*16+u];
        float4 hv = hh4[l4*16+u];
        acc = fmaf(w4.x,hv.x, fmaf(w4.y,hv.y, fmaf(w4.z,hv.z, fmaf(w4.w,hv.w, acc))));
      }
      acc += __shfl_xor(acc,1);
      acc += __shfl_xor(acc,2);
      if (l4==0) cstore(&ws_wh[b*H3_ + c*48 + d], acc + bh2h_reg);
    }
  }
  int target = 16;
  groupbar_full(ctr, target);

  // ---------------- scan ----------------
  for (int t = 0; t < T_; t++){
    const int p  = t & 1;
    const int pn = p ^ 1;

    // ---- G phase (redundant across the 16 blocks of this batch group)
    float wh0, wh1, wh2;
    {
      const float* whr = ws_wh + p*(B_*H3_) + b*H3_;
      const float* pl  = ws_pl + p*(B_*H_)  + b*H_;
      wh0 = cload(&whr[tid]);
      wh1 = cload(&whr[tid+256]);
      wh2 = cload(&whr[tid+512]) + cload(&pl[tid]);  // plastic added pre-LN
      float s1 = wh0+wh1+wh2;
      float s2 = wh0*wh0+wh1*wh1+wh2*wh2;
      #pragma unroll
      for (int off=32; off>0; off>>=1){ s1 += __shfl_xor(s1,off); s2 += __shfl_xor(s2,off); }
      if (lane==0){ red_s[wv]=s1; red_s[4+wv]=s2; }
      __syncthreads();
      s1 = red_s[0]+red_s[1]+red_s[2]+red_s[3];
      s2 = red_s[4]+red_s[5]+red_s[6]+red_s[7];
      __syncthreads();
      float mu  = s1*(1.0f/768.0f);
      float var = s2*(1.0f/768.0f) - mu*mu;
      float rs  = rsqrtf(var + 1e-5f);
      const float* wxr = ws_wx + ((size_t)(t*B_ + b))*H3_;
      pre_s[tid]     = wxr[tid]     + (wh0-mu)*rs*lnhg_s[tid]     + lnhb_s[tid];
      pre_s[tid+256] = wxr[tid+256] + (wh1-mu)*rs*lnhg_s[tid+256] + lnhb_s[tid+256];
      pre_s[tid+512] = wxr[tid+512] + (wh2-mu)*rs*lnhg_s[tid+512] + lnhb_s[tid+512];
    }
    // gates (same-thread indices only; no sync needed before)
    {
      float z   = sigmf(pre_s[tid]);
      float r   = sigmf(pre_s[H_+tid]);
      float dv  = pre_s[2*H_+tid];
      float vo  = v_s[tid];
      float vn  = fmaf(z, dv - vo, vo);       // (1-z)v + z dv
      float hn  = fmaxf(vn, 0.0f);
      float teo = te_s[tid];
      float ten = fmaf(r, h_s[tid] - teo, teo);  // (1-r)te + r h_old
      v_s[tid] = vn; hn_s[tid] = hn; ten_s[tid] = ten;
      h_s[tid] = hn; te_s[tid] = ten;
    }
    __syncthreads();
    // mod = relu(h_new @ Wh2mod^T + b); chunk order rotated by mk -> no bank conflict
    {
      const float4* hn4 = (const float4*)hn_s;
      float acc = 0.f;
      #pragma unroll
      for (int j = 0; j < 8; j++){
        float4 hv = hn4[l8*8 + ((j+mk7)&7)];
        float4 w4 = wm[j];
        acc = fmaf(w4.x,hv.x, fmaf(w4.y,hv.y, fmaf(w4.z,hv.z, fmaf(w4.w,hv.w, acc))));
      }
      acc += __shfl_xor(acc,1); acc += __shfl_xor(acc,2); acc += __shfl_xor(acc,4);
      if (l8==0) mod_s[mk] = fmaxf(acc + bh2m, 0.0f);
    }
    __syncthreads();
    if (tid < 32){
      float mv = mod_s[tid];
      float p0 = mv*wmA, p1 = mv*wmB;
      #pragma unroll
      for (int off=16; off>0; off>>=1){ p0 += __shfl_xor(p0,off); p1 += __shfl_xor(p1,off); }
      if (tid==0){ sm_s[0] = sigmf(p0+bm0); sm_s[1] = p1+bm1; }
    }
    __syncthreads();
    const float s_b = sm_s[0];
    const float m_b = sm_s[1];

    if (c == 0){   // designated writer for this batch
      out[OFF_OUTS + ((size_t)(t*B_+b))*H_ + tid] = hn_s[tid];
      if (tid < R_) out[OFF_MODS + (size_t)(t*B_+b)*R_ + tid] = mod_s[tid];
      if (t == T_-1){
        out[OFF_V  + b*H_ + tid] = v_s[tid];
        out[OFF_H  + b*H_ + tid] = hn_s[tid];
        out[OFF_TE + b*H_ + tid] = ten_s[tid];
      }
    }

    // ---- U phase: register-resident tE/dU update for my 16 rows,
    //      fused plastic_{t+1}; global write ONLY at the final step.
    {
      const float4* hn4 = (const float4*)hn_s;
      const float4* te4 = (const float4*)ten_s;
      float4 hj = hn4[lane];
      float4 tj = te4[lane];
      #pragma unroll
      for (int rr = 0; rr < 4; rr++){
        int i = c*16 + rr*4 + wv;
        float4 du = duR[rr];
        float4 tE = tER[rr];
        float4 w  = wreg[rr];
        float hni  = hn_s[i];
        float teni = ten_s[i];
        float4 nd, nt;
        float acc;
        { float o_ = hni*tj.x - teni*hj.x;
          float tn = fmaf(s_b, o_ - tE.x, tE.x);
          float dn = fmaf(tau, fmaf(m_b, tn, -du.x), du.x);
          float up =  fmaxf(1.0f - w.x, 0.0f)*inv_spa;
          float lo = -fmaxf(1.0f + w.x, 0.0f)*inv_spa;
          dn = fminf(dn, up); dn = fmaxf(dn, lo);
          nt.x = tn; nd.x = dn; acc = dn*hj.x; }
        { float o_ = hni*tj.y - teni*hj.y;
          float tn = fmaf(s_b, o_ - tE.y, tE.y);
          float dn = fmaf(tau, fmaf(m_b, tn, -du.y), du.y);
          float up =  fmaxf(1.0f - w.y, 0.0f)*inv_spa;
          float lo = -fmaxf(1.0f + w.y, 0.0f)*inv_spa;
          dn = fminf(dn, up); dn = fmaxf(dn, lo);
          nt.y = tn; nd.y = dn; acc = fmaf(dn, hj.y, acc); }
        { float o_ = hni*tj.z - teni*hj.z;
          float tn = fmaf(s_b, o_ - tE.z, tE.z);
          float dn = fmaf(tau, fmaf(m_b, tn, -du.z), du.z);
          float up =  fmaxf(1.0f - w.z, 0.0f)*inv_spa;
          float lo = -fmaxf(1.0f + w.z, 0.0f)*inv_spa;
          dn = fminf(dn, up); dn = fmaxf(dn, lo);
          nt.z = tn; nd.z = dn; acc = fmaf(dn, hj.z, acc); }
        { float o_ = hni*tj.w - teni*hj.w;
          float tn = fmaf(s_b, o_ - tE.w, tE.w);
          float dn = fmaf(tau, fmaf(m_b, tn, -du.w), du.w);
          float up =  fmaxf(1.0f - w.w, 0.0f)*inv_spa;
          float lo = -fmaxf(1.0f + w.w, 0.0f)*inv_spa;
          dn = fminf(dn, up); dn = fmaxf(dn, lo);
          nt.w = tn; nd.w = dn; acc = fmaf(dn, hj.w, acc); }
        duR[rr] = nd;
        tER[rr] = nt;
        if (t == T_-1){
          size_t rowo = ((size_t)(b*H_ + i))*H_;
          ((float4*)(out + OFF_DU + rowo))[lane] = nd;
          ((float4*)(out + OFF_TT + rowo))[lane] = nt;
        }
        #pragma unroll
        for (int off=32; off>0; off>>=1) acc += __shfl_xor(acc,off);
        if (lane==0) cstore(&ws_pl[pn*(B_*H_) + b*H_ + i], sp_a*acc);  // plastic t+1
      }
    }

    // ---- Wh_raw for t+1 (my 48 features, own batch, W from LDS) + barrier
    if (t < T_-1){
      if (tid < 192){
        int d = tid>>2, l4 = tid&3;
        const float4* wr4 = (const float4*)(wrow_s + d*260);
        const float4* hh4 = (const float4*)hn_s;
        float acc = 0.f;
        #pragma unroll
        for (int u = 0; u < 16; u++){
          float4 w4 = wr4[l4*16+u];
          float4 hv = hh4[l4*16+u];
          acc = fmaf(w4.x,hv.x, fmaf(w4.y,hv.y, fmaf(w4.z,hv.z, fmaf(w4.w,hv.w, acc))));
        }
        acc += __shfl_xor(acc,1);
        acc += __shfl_xor(acc,2);
        if (l4==0) cstore(&ws_wh[pn*(B_*H3_) + b*H3_ + c*48 + d], acc + bh2h_reg);
      }
      target += 16;
      groupbar_light(ctr, target);
    }
  }

  // ---- self-reset of group counters for the next launch.
  __syncthreads();
  if (threadIdx.x == 0){
    int d = __hip_atomic_fetch_add(dctr, 1, __ATOMIC_RELAXED, __HIP_MEMORY_SCOPE_AGENT);
    if (d == 15){
      __hip_atomic_store(ctr,  0, __ATOMIC_RELAXED, __HIP_MEMORY_SCOPE_AGENT);
      __hip_atomic_store(dctr, 0, __ATOMIC_RELAXED, __HIP_MEMORY_SCOPE_AGENT);
    }
  }
}

extern "C" void kernel_launch(void* const* d_in, const int* in_sizes, int n_in,
                              void* d_out, int out_size, void* d_ws, size_t ws_size,
                              hipStream_t stream)
{
  const float* x      = (const float*)d_in[0];
  const float* h0     = (const float*)d_in[1];
  const float* v0     = (const float*)d_in[2];
  const float* dU0    = (const float*)d_in[3];
  const float* te0    = (const float*)d_in[4];
  const float* tE0    = (const float*)d_in[5];
  const float* Wx2h   = (const float*)d_in[6];
  const float* bx2h   = (const float*)d_in[7];
  const float* Wh2h   = (const float*)d_in[8];
  const float* bh2h   = (const float*)d_in[9];
  const float* lnxg   = (const float*)d_in[10];
  const float* lnxb   = (const float*)d_in[11];
  const float* lnhg   = (const float*)d_in[12];
  const float* lnhb   = (const float*)d_in[13];
  const float* Wh2mod = (const float*)d_in[14];
  const float* bh2mod = (const float*)d_in[15];
  const float* Wmod2h = (const float*)d_in[16];
  const float* bmod2h = (const float*)d_in[17];
  const float* alpha  = (const float*)d_in[18];
  const float* tauU   = (const float*)d_in[19];
  float* out = (float*)d_out;

  sgru_kernel<<<dim3(256), dim3(256), 0, stream>>>(
      x, h0, v0, dU0, te0, tE0, Wx2h, bx2h, Wh2h, bh2h,
      lnxg, lnxb, lnhg, lnhb, Wh2mod, bh2mod, Wmod2h, bmod2h,
      alpha, tauU, out);
}